// Round 1
// baseline (220.216 us; speedup 1.0000x reference)
//
#include <hip/hip_runtime.h>
#include <hip/hip_bf16.h>

#define B_    32
#define CDD_  5
#define HIS_  50
#define L_    32
#define LVL_  2
#define H_    256
#define K_    5
#define NCDD  (B_*CDD_)        // 160
#define NHIS  (B_*HIS_)        // 1600
#define NROWS (NCDD + NHIS)    // 1760
#define SLAB  (L_*LVL_*H_)     // 16384 floats per (b,his) embedding slab
#define OUT0  ((size_t)NCDD*K_*SLAB)  // 13,107,200 floats

#define ROWS_A 8               // rows per block in kernel A (220 blocks)

// ---------------------------------------------------------------------------
// Kernel A: Y[r] = l2norm(x_r @ W^T + b) for 1760 combined rows
// (rows 0..159 = cdd_repr, rows 160..1759 = his_repr)
// 8 rows per block; thread t owns output column t (streams W row t as float4).
// x rows are wave-uniform -> read via scalar path (s_load), zero LDS traffic
// in the main loop; v_fma takes the SGPR x operand directly.
// ---------------------------------------------------------------------------
__global__ __launch_bounds__(256) void proj_norm_kernel(
    const float* __restrict__ cdd, const float* __restrict__ his,
    const float* __restrict__ Wm, const float* __restrict__ bias,
    float* __restrict__ Y)
{
    __shared__ float part[ROWS_A][4];
    __shared__ float inv[ROWS_A];
    const int t = threadIdx.x;
    const int r0 = blockIdx.x * ROWS_A;

    // uniform (blockIdx-derived) row base pointers
    const float4* xr[ROWS_A];
    #pragma unroll
    for (int r = 0; r < ROWS_A; ++r) {
        int row = r0 + r;
        const float* p = (row < NCDD) ? (cdd + (size_t)row * H_)
                                      : (his + (size_t)(row - NCDD) * H_);
        xr[r] = (const float4*)p;
    }

    float acc[ROWS_A];
    #pragma unroll
    for (int r = 0; r < ROWS_A; ++r) acc[r] = 0.f;

    const float4* wrow = (const float4*)(Wm + (size_t)t * H_);

    #pragma unroll 4
    for (int ch = 0; ch < H_ / 8; ++ch) {      // 32 chunks of 8 floats
        float4 w0 = wrow[2*ch];
        float4 w1 = wrow[2*ch + 1];
        #pragma unroll
        for (int r = 0; r < ROWS_A; ++r) {
            float4 xa = xr[r][2*ch];           // uniform -> s_load_dwordx4
            float4 xb = xr[r][2*ch + 1];
            acc[r] += w0.x*xa.x + w0.y*xa.y + w0.z*xa.z + w0.w*xa.w
                    + w1.x*xb.x + w1.y*xb.y + w1.z*xb.z + w1.w*xb.w;
        }
    }

    const float bt = bias[t];
    float y[ROWS_A], ss[ROWS_A];
    #pragma unroll
    for (int r = 0; r < ROWS_A; ++r) { y[r] = acc[r] + bt; ss[r] = y[r]*y[r]; }

    // block reduce sum-of-squares per row (wave shuffle, then 4 partials)
    const int wave = t >> 6, lane = t & 63;
    #pragma unroll
    for (int off = 32; off; off >>= 1) {
        #pragma unroll
        for (int r = 0; r < ROWS_A; ++r) ss[r] += __shfl_down(ss[r], off);
    }
    if (lane == 0) {
        #pragma unroll
        for (int r = 0; r < ROWS_A; ++r) part[r][wave] = ss[r];
    }
    __syncthreads();
    if (t < ROWS_A) {
        float s = part[t][0] + part[t][1] + part[t][2] + part[t][3];
        inv[t] = 1.0f / fmaxf(sqrtf(s), 1e-12f);   // matches F.normalize eps
    }
    __syncthreads();

    float* yp = Y + (size_t)r0 * H_ + t;
    #pragma unroll
    for (int r = 0; r < ROWS_A; ++r) yp[r * H_] = y[r] * inv[r];
}

// ---------------------------------------------------------------------------
// Kernel B: per (b,cdd): 50 cosine scores, top-5 (desc, first-index ties),
// threshold weights, write idx/w to ws and the mask output (as float).
// Scores: each wave owns h = wave, wave+4, ... (shuffle dot-reduce).
// Top-k: wave 0 does 5 rounds of (val,idx) butterfly max, min-index ties.
// ---------------------------------------------------------------------------
__global__ __launch_bounds__(256) void attn_topk_kernel(
    const float* __restrict__ Y, const int* __restrict__ mask,
    int* __restrict__ idx_ws, float* __restrict__ w_ws,
    float* __restrict__ mask_out)
{
    const int bc = blockIdx.x;          // 0..159  (= b*CDD + cd)
    const int b  = bc / CDD_;
    __shared__ float cs[H_];
    __shared__ float scores[HIS_];
    __shared__ int   sidx[K_];
    const int t = threadIdx.x;

    cs[t] = Y[(size_t)bc * H_ + t];     // cdd rows occupy Y[0..160)
    __syncthreads();

    const int wave = t >> 6, lane = t & 63;
    for (int h = wave; h < HIS_; h += 4) {
        const float4* hv = (const float4*)(Y + (size_t)(NCDD + b * HIS_ + h) * H_);
        float4 x  = hv[lane];
        float4 c4 = ((float4*)cs)[lane];
        float p = x.x*c4.x + x.y*c4.y + x.z*c4.z + x.w*c4.w;
        #pragma unroll
        for (int off = 32; off; off >>= 1) p += __shfl_down(p, off);
        if (lane == 0) scores[h] = p;
    }
    __syncthreads();

    if (wave == 0) {
        float v = (lane < HIS_) ? scores[lane] : -1e30f;
        #pragma unroll
        for (int k = 0; k < K_; ++k) {
            float mv = v; int mi = lane;
            #pragma unroll
            for (int off = 32; off; off >>= 1) {
                float ov = __shfl_xor(mv, off);
                int   oi = __shfl_xor(mi, off);
                if (ov > mv || (ov == mv && oi < mi)) { mv = ov; mi = oi; }
            }
            // all lanes now agree on (mv, mi); strictly-greater scan semantics
            if (lane == 0) {
                sidx[k] = mi;
                idx_ws[bc * K_ + k] = mi;
                w_ws[bc * K_ + k]   = (mv < 0.1f) ? 0.0f : mv;
            }
            if (lane == mi) v = -1e30f;   // remove winner
        }
    }
    __syncthreads();

    if (t < K_ * L_) {
        int k = t / L_, l = t % L_;
        mask_out[((size_t)bc * K_ + k) * L_ + l] =
            (float)mask[((size_t)(b * HIS_ + sidx[k])) * L_ + l];
    }
}

// ---------------------------------------------------------------------------
// Kernel C: out0[(bc,k)] = emb[b, idx[bc,k]] * w[bc,k]  (scaled 64KB memcpy)
// 8 slices per (bc,k) slab -> 6400 blocks; 2 float4 per thread.
// ---------------------------------------------------------------------------
__global__ __launch_bounds__(256) void gather_scale_kernel(
    const float* __restrict__ emb, const int* __restrict__ idx_ws,
    const float* __restrict__ w_ws, float* __restrict__ out)
{
    const int gb    = blockIdx.x;
    const int slice = gb & 7;
    const int bck   = gb >> 3;          // 0..799 (= bc*K + k)
    const int bc    = bck / K_;
    const int b     = bc / CDD_;
    const int i     = idx_ws[bck];
    const float w   = w_ws[bck];

    const float4* src = (const float4*)(emb + (size_t)(b * HIS_ + i) * SLAB);
    float4*       dst = (float4*)(out + (size_t)bck * SLAB);
    const int base = slice * 512 + threadIdx.x;     // float4 index in [0,4096)

    float4 v0 = src[base];
    float4 v1 = src[base + 256];
    v0.x *= w; v0.y *= w; v0.z *= w; v0.w *= w;
    v1.x *= w; v1.y *= w; v1.z *= w; v1.w *= w;
    dst[base]       = v0;
    dst[base + 256] = v1;
}

// ---------------------------------------------------------------------------
extern "C" void kernel_launch(void* const* d_in, const int* in_sizes, int n_in,
                              void* d_out, int out_size, void* d_ws, size_t ws_size,
                              hipStream_t stream) {
    const float* cdd  = (const float*)d_in[0];
    const float* his  = (const float*)d_in[1];
    const float* emb  = (const float*)d_in[2];
    const int*   mask = (const int*)  d_in[3];
    const float* Wm   = (const float*)d_in[4];
    const float* bias = (const float*)d_in[5];
    float* out = (float*)d_out;

    // workspace layout
    float* Y      = (float*)d_ws;                                  // 1760*256 f32
    int*   idx_ws = (int*)  ((char*)d_ws + (size_t)NROWS*H_*4);    // 800 i32
    float* w_ws   = (float*)((char*)d_ws + (size_t)NROWS*H_*4 + 800*4); // 800 f32

    proj_norm_kernel<<<NROWS / ROWS_A, 256, 0, stream>>>(cdd, his, Wm, bias, Y);
    attn_topk_kernel<<<NCDD, 256, 0, stream>>>(Y, mask, idx_ws, w_ws, out + OUT0);
    gather_scale_kernel<<<NCDD * K_ * 8, 256, 0, stream>>>(emb, idx_ws, w_ws, out);
}

// Round 2
// 195.120 us; speedup vs baseline: 1.1286x; 1.1286x over previous
//
#include <hip/hip_runtime.h>
#include <hip/hip_bf16.h>

#define B_    32
#define CDD_  5
#define HIS_  50
#define L_    32
#define LVL_  2
#define H_    256
#define K_    5
#define NCDD  (B_*CDD_)        // 160
#define NHIS  (B_*HIS_)        // 1600
#define NROWS (NCDD + NHIS)    // 1760
#define SLAB  (L_*LVL_*H_)     // 16384 floats per (b,his) embedding slab
#define OUT0  ((size_t)NCDD*K_*SLAB)  // 13,107,200 floats

// ---------------------------------------------------------------------------
// Kernel A: Y[r] = l2norm(x_r @ W^T + b) for 1760 combined rows
// (rows 0..159 = cdd_repr, rows 160..1759 = his_repr)
// 4 rows per block; thread t owns output column t (reads W row t as float4).
// x rows staged in LDS; same-address ds_read_b128 across the wave is a free
// broadcast (round-1 lesson: the global/scalar path for x is 3x slower).
// ---------------------------------------------------------------------------
__global__ __launch_bounds__(256) void proj_norm_kernel(
    const float* __restrict__ cdd, const float* __restrict__ his,
    const float* __restrict__ Wm, const float* __restrict__ bias,
    float* __restrict__ Y)
{
    __shared__ float xs[4][H_];
    __shared__ float part[4][4];
    __shared__ float inv[4];
    const int t = threadIdx.x;
    const int r0 = blockIdx.x * 4;

    {   // stage 4 input rows (coalesced float4)
        int rr = t >> 6, cc = t & 63;
        int row = r0 + rr;
        const float* src = (row < NCDD) ? (cdd + (size_t)row * H_)
                                        : (his + (size_t)(row - NCDD) * H_);
        ((float4*)xs[rr])[cc] = ((const float4*)src)[cc];
    }
    __syncthreads();

    float a0 = 0.f, a1 = 0.f, a2 = 0.f, a3 = 0.f;
    const float4* wrow = (const float4*)(Wm + (size_t)t * H_);
    #pragma unroll 8
    for (int c = 0; c < H_ / 4; ++c) {
        float4 wv = wrow[c];
        float4 x0 = ((float4*)xs[0])[c];
        float4 x1 = ((float4*)xs[1])[c];
        float4 x2 = ((float4*)xs[2])[c];
        float4 x3 = ((float4*)xs[3])[c];
        a0 += wv.x*x0.x + wv.y*x0.y + wv.z*x0.z + wv.w*x0.w;
        a1 += wv.x*x1.x + wv.y*x1.y + wv.z*x1.z + wv.w*x1.w;
        a2 += wv.x*x2.x + wv.y*x2.y + wv.z*x2.z + wv.w*x2.w;
        a3 += wv.x*x3.x + wv.y*x3.y + wv.z*x3.z + wv.w*x3.w;
    }
    const float bt = bias[t];
    float y0 = a0 + bt, y1 = a1 + bt, y2 = a2 + bt, y3 = a3 + bt;

    // block reduce sum-of-squares per row (wave shuffle, then 4 partials)
    const int wave = t >> 6, lane = t & 63;
    float s0 = y0*y0, s1 = y1*y1, s2 = y2*y2, s3 = y3*y3;
    #pragma unroll
    for (int off = 32; off; off >>= 1) {
        s0 += __shfl_down(s0, off);
        s1 += __shfl_down(s1, off);
        s2 += __shfl_down(s2, off);
        s3 += __shfl_down(s3, off);
    }
    if (lane == 0) { part[0][wave] = s0; part[1][wave] = s1;
                     part[2][wave] = s2; part[3][wave] = s3; }
    __syncthreads();
    if (t < 4) {
        float s = part[t][0] + part[t][1] + part[t][2] + part[t][3];
        inv[t] = 1.0f / fmaxf(sqrtf(s), 1e-12f);   // matches F.normalize eps
    }
    __syncthreads();

    float* yr = Y + (size_t)r0 * H_ + t;
    yr[0 * H_] = y0 * inv[0];
    yr[1 * H_] = y1 * inv[1];
    yr[2 * H_] = y2 * inv[2];
    yr[3 * H_] = y3 * inv[3];
}

// ---------------------------------------------------------------------------
// Kernel B: per (b,cdd): 50 cosine scores, top-5 (desc, first-index ties),
// threshold weights, write idx/w to ws and the mask output (as float).
// Scores: each wave owns h = wave, wave+4, ... (shuffle dot-reduce).
// Top-k: wave 0 does 5 rounds of (val,idx) butterfly max, min-index ties
// (matches the strictly-greater first-index-wins serial scan semantics).
// ---------------------------------------------------------------------------
__global__ __launch_bounds__(256) void attn_topk_kernel(
    const float* __restrict__ Y, const int* __restrict__ mask,
    int* __restrict__ idx_ws, float* __restrict__ w_ws,
    float* __restrict__ mask_out)
{
    const int bc = blockIdx.x;          // 0..159  (= b*CDD + cd)
    const int b  = bc / CDD_;
    __shared__ float cs[H_];
    __shared__ float scores[HIS_];
    __shared__ int   sidx[K_];
    const int t = threadIdx.x;

    cs[t] = Y[(size_t)bc * H_ + t];     // cdd rows occupy Y[0..160)
    __syncthreads();

    const int wave = t >> 6, lane = t & 63;
    for (int h = wave; h < HIS_; h += 4) {
        const float4* hv = (const float4*)(Y + (size_t)(NCDD + b * HIS_ + h) * H_);
        float4 x  = hv[lane];
        float4 c4 = ((float4*)cs)[lane];
        float p = x.x*c4.x + x.y*c4.y + x.z*c4.z + x.w*c4.w;
        #pragma unroll
        for (int off = 32; off; off >>= 1) p += __shfl_down(p, off);
        if (lane == 0) scores[h] = p;
    }
    __syncthreads();

    if (wave == 0) {
        float v = (lane < HIS_) ? scores[lane] : -1e30f;
        #pragma unroll
        for (int k = 0; k < K_; ++k) {
            float mv = v; int mi = lane;
            #pragma unroll
            for (int off = 32; off; off >>= 1) {
                float ov = __shfl_xor(mv, off);
                int   oi = __shfl_xor(mi, off);
                if (ov > mv || (ov == mv && oi < mi)) { mv = ov; mi = oi; }
            }
            // all lanes agree on (mv, mi)
            if (lane == 0) {
                sidx[k] = mi;
                idx_ws[bc * K_ + k] = mi;
                w_ws[bc * K_ + k]   = (mv < 0.1f) ? 0.0f : mv;
            }
            if (lane == mi) v = -1e30f;   // remove winner
        }
    }
    __syncthreads();

    if (t < K_ * L_) {
        int k = t / L_, l = t % L_;
        mask_out[((size_t)bc * K_ + k) * L_ + l] =
            (float)mask[((size_t)(b * HIS_ + sidx[k])) * L_ + l];
    }
}

// ---------------------------------------------------------------------------
// Kernel C: out0[(bc,k)] = emb[b, idx[bc,k]] * w[bc,k]  (scaled 64KB memcpy)
// 8 slices per (bc,k) slab -> 6400 blocks; 2 float4 per thread.
// ---------------------------------------------------------------------------
__global__ __launch_bounds__(256) void gather_scale_kernel(
    const float* __restrict__ emb, const int* __restrict__ idx_ws,
    const float* __restrict__ w_ws, float* __restrict__ out)
{
    const int gb    = blockIdx.x;
    const int slice = gb & 7;
    const int bck   = gb >> 3;          // 0..799 (= bc*K + k)
    const int bc    = bck / K_;
    const int b     = bc / CDD_;
    const int i     = idx_ws[bck];
    const float w   = w_ws[bck];

    const float4* src = (const float4*)(emb + (size_t)(b * HIS_ + i) * SLAB);
    float4*       dst = (float4*)(out + (size_t)bck * SLAB);
    const int base = slice * 512 + threadIdx.x;     // float4 index in [0,4096)

    float4 v0 = src[base];
    float4 v1 = src[base + 256];
    v0.x *= w; v0.y *= w; v0.z *= w; v0.w *= w;
    v1.x *= w; v1.y *= w; v1.z *= w; v1.w *= w;
    dst[base]       = v0;
    dst[base + 256] = v1;
}

// ---------------------------------------------------------------------------
extern "C" void kernel_launch(void* const* d_in, const int* in_sizes, int n_in,
                              void* d_out, int out_size, void* d_ws, size_t ws_size,
                              hipStream_t stream) {
    const float* cdd  = (const float*)d_in[0];
    const float* his  = (const float*)d_in[1];
    const float* emb  = (const float*)d_in[2];
    const int*   mask = (const int*)  d_in[3];
    const float* Wm   = (const float*)d_in[4];
    const float* bias = (const float*)d_in[5];
    float* out = (float*)d_out;

    // workspace layout
    float* Y      = (float*)d_ws;                                  // 1760*256 f32
    int*   idx_ws = (int*)  ((char*)d_ws + (size_t)NROWS*H_*4);    // 800 i32
    float* w_ws   = (float*)((char*)d_ws + (size_t)NROWS*H_*4 + 800*4); // 800 f32

    proj_norm_kernel<<<NROWS / 4, 256, 0, stream>>>(cdd, his, Wm, bias, Y);
    attn_topk_kernel<<<NCDD, 256, 0, stream>>>(Y, mask, idx_ws, w_ws, out + OUT0);
    gather_scale_kernel<<<NCDD * K_ * 8, 256, 0, stream>>>(emb, idx_ws, w_ws, out);
}